// Round 3
// baseline (1909.062 us; speedup 1.0000x reference)
//
#include <hip/hip_runtime.h>
#include <stdint.h>

// Problem constants (match reference)
constexpr int B  = 8;
constexpr int R  = 1024;
constexpr int C  = 1024;
constexpr int RC = R * C;
constexpr float GSR = 80.0f / 1024.0f;   // grid_size_row = 0.078125 (exact in f32)
constexpr float GSC = 80.0f / 1024.0f;   // grid_size_col identical
constexpr float PIXEL_THRESHOLD = 0.05f;

// Native clang vector types — accepted by __builtin_nontemporal_load
// (HIP's float4/int4 are structs and are NOT).
typedef float f32x4 __attribute__((ext_vector_type(4)));
typedef int   i32x4 __attribute__((ext_vector_type(4)));

// Scatter: each thread handles 4 consecutive columns (16B vector loads).
// For each foreground source, 4 HW float atomics into out[(b, tr, tc, 0..3)].
// unsafeAtomicAdd -> global_atomic_add_f32 (no CAS loop, fire-and-forget).
__global__ __launch_bounds__(256) void scatter_kernel(
    const int*   __restrict__ voxel,   // (B,R,C)
    const float* __restrict__ pixel,   // (B,R,C)
    const float* __restrict__ conf,    // (B,R,C)
    const float* __restrict__ off,     // (B,2,R,C)
    const float* __restrict__ vel,     // (B,2,R,C)
    float*       __restrict__ out)     // (B,R,C,4) accumulator (pre-zeroed)
{
    const int64_t total4 = (int64_t)B * RC / 4;
    const int64_t stride = (int64_t)gridDim.x * blockDim.x;
    for (int64_t t = (int64_t)blockIdx.x * blockDim.x + threadIdx.x;
         t < total4; t += stride) {
        const int64_t i  = t * 4;              // element index into (B,R,C)
        const int b  = (int)(i / RC);
        const int rc = (int)(i - (int64_t)b * RC);
        const int r  = rc / C;
        const int c0 = rc % C;                  // multiple of 4

        // Single-use input streams: nontemporal loads keep L2/L3 free
        // for the atomic accumulator.
        const f32x4 px = __builtin_nontemporal_load((const f32x4*)(pixel + i));
        const i32x4 vx = __builtin_nontemporal_load((const i32x4*)(voxel + i));
        const f32x4 cf = __builtin_nontemporal_load((const f32x4*)(conf  + i));
        const int64_t ob = (int64_t)b * 2 * RC + rc;
        const f32x4 o0 = __builtin_nontemporal_load((const f32x4*)(off + ob));      // row offsets
        const f32x4 o1 = __builtin_nontemporal_load((const f32x4*)(off + ob + RC)); // col offsets
        const f32x4 v0 = __builtin_nontemporal_load((const f32x4*)(vel + ob));      // vel row
        const f32x4 v1 = __builtin_nontemporal_load((const f32x4*)(vel + ob + RC)); // vel col

        #pragma unroll
        for (int j = 0; j < 4; ++j) {
            if (px[j] > PIXEL_THRESHOLD && vx[j] >= 0) {
                // round-half-even (v_rndne) matches jnp.round; IEEE divide
                float drf = rintf(o0[j] / GSR);
                float dcf = rintf(o1[j] / GSC);
                // clamp in float to keep int conversion safe, then int clip
                drf = fminf(fmaxf(drf, -2.0f * R), 2.0f * R);
                dcf = fminf(fmaxf(dcf, -2.0f * C), 2.0f * C);
                int tr = r      + (int)drf;
                int tc = c0 + j + (int)dcf;
                tr = min(max(tr, 0), R - 1);
                tc = min(max(tc, 0), C - 1);
                float* p = out + ((int64_t)b * RC + (int64_t)tr * C + tc) * 4;
                unsafeAtomicAdd(p + 0, 1.0f);     // HW global_atomic_add_f32
                unsafeAtomicAdd(p + 1, cf[j]);
                unsafeAtomicAdd(p + 2, v0[j]);
                unsafeAtomicAdd(p + 3, v1[j]);
            }
        }
    }
}

// Finalize in place: cells with count==0 become (-0.1, -0.1, -0.1, -0.1).
// Cells with count>0 already hold the correct aggregate -> no write needed.
__global__ __launch_bounds__(256) void finalize_kernel(float* __restrict__ out)
{
    const int64_t total = (int64_t)B * RC;   // one float4 per cell
    const int64_t stride = (int64_t)gridDim.x * blockDim.x;
    f32x4* o4 = (f32x4*)out;
    for (int64_t t = (int64_t)blockIdx.x * blockDim.x + threadIdx.x;
         t < total; t += stride) {
        const float cnt = ((const float*)(o4 + t))[0];   // count channel
        if (cnt <= 0.0f) {
            f32x4 neg = {-0.1f, -0.1f, -0.1f, -0.1f};
            o4[t] = neg;
        }
    }
}

extern "C" void kernel_launch(void* const* d_in, const int* in_sizes, int n_in,
                              void* d_out, int out_size, void* d_ws, size_t ws_size,
                              hipStream_t stream) {
    const int*   voxel = (const int*)  d_in[0];
    const float* pixel = (const float*)d_in[1];
    const float* conf  = (const float*)d_in[2];
    const float* off   = (const float*)d_in[3];
    // d_in[4] = view_index — UNUSED by the reference; never touched.
    const float* vel   = (const float*)d_in[5];
    float* out = (float*)d_out;

    // Harness poisons d_out with 0xAA before every call — zero it.
    (void)hipMemsetAsync(out, 0, (size_t)B * RC * 4 * sizeof(float), stream);

    const int block = 256;
    // scatter: B*RC/4 = 2,097,152 threads -> 8192 blocks exact
    const int sgrid = (int)(((int64_t)B * RC / 4 + block - 1) / block);
    scatter_kernel<<<sgrid, block, 0, stream>>>(voxel, pixel, conf, off, vel, out);

    // finalize: B*RC = 8,388,608 cells -> grid-stride over 16384 blocks
    const int fgrid = 16384;
    finalize_kernel<<<fgrid, block, 0, stream>>>(out);
}